// Round 7
// baseline (109.556 us; speedup 1.0000x reference)
//
#include <hip/hip_runtime.h>
#include <math.h>

// Problem constants
constexpr int NH     = 778;    // hand verts per batch
constexpr int T      = 16;     // hand points per SGPR tile
constexpr int G      = 4;      // tiles per block -> 64 hand points / block
constexpr int NBX    = 13;     // ceil(49 tiles / 4)
constexpr int NHPAD  = NBX * G * T;  // 832 padded hand points
constexpr int BLK    = 256;    // 4 waves
constexpr int CHUNKP = 2560;   // obj points per block chunk
constexpr int LPP    = CHUNKP / BLK;   // 10 obj float4s per lane (40 VGPRs)

// ---------------------------------------------------------------------------
// Prepass: obj tf[b][j] = (x,y,z,|o|^2) (sentinel w=3.4e38 past V),
//          hand tf[b][i] = (-2hx,-2hy,-2hz,|h|^2) (pad i>=NH clamped),
//          minb init to 0x7F7F7F7F.
// ---------------------------------------------------------------------------
__global__ __launch_bounds__(256) void transform_kernel(
    const float* __restrict__ hand,  // [B, NH, 3]
    const float* __restrict__ obj,   // [B, V, 3]
    float4* __restrict__ otf,        // [B, Vpad]
    float4* __restrict__ htf,        // [B, NHPAD]
    unsigned int* __restrict__ minb, // [B*NH]
    int V, int Vpad, int B)
{
    const int i = blockIdx.x * 256 + threadIdx.x;
    if (i < B * NH) minb[i] = 0x7F7F7F7Fu;
    if (i < B * NHPAD) {
        const int b = i / NHPAD;
        const int h = min(i - b * NHPAD, NH - 1);
        const float* p = hand + ((size_t)b * NH + h) * 3;
        const float x = p[0], y = p[1], z = p[2];
        htf[i] = make_float4(-2.f * x, -2.f * y, -2.f * z,
                             fmaf(x, x, fmaf(y, y, z * z)));
    }
    if (i < B * Vpad) {
        const int b = i / Vpad;
        const int j = i - b * Vpad;
        if (j < V) {
            const float* p = obj + ((size_t)b * V + j) * 3;
            const float x = p[0], y = p[1], z = p[2];
            otf[i] = make_float4(x, y, z, fmaf(x, x, fmaf(y, y, z * z)));
        } else {
            otf[i] = make_float4(0.f, 0.f, 0.f, 3.4e38f);  // never the min
        }
    }
}

// ---------------------------------------------------------------------------
// Main NN kernel (R6 post-mortem: shfl-xor epilogue was 96 ds_swizzle/wave on
// the shared per-CU DS pipe = the real bottleneck, ~23us of DS time).
// R7 changes: (1) G=4 hand tiles per block reuse the same 40-VGPR obj stash ->
// obj traffic /4 and epilogue amortized /4; (2) epilogue = LDS transpose
// (stride-65 rows: conflict-free b32) + 2 swizzles = 34 DS instr/tile vs 192.
// Main loop per pair: fma,fma,fma,min (one SGPR operand per v_fma).
// ---------------------------------------------------------------------------
__global__ __launch_bounds__(BLK, 3) void nn_min_kernel(
    const float4* __restrict__ otf,  // [B, Vpad] (x,y,z,q)
    const float4* __restrict__ htf,  // [B, NHPAD] (-2x,-2y,-2z,q)
    unsigned int* __restrict__ minb, // [B*NH]
    int Vpad)
{
    __shared__ float s_red[4][16 * 65];   // per-wave transpose scratch
    const int bx  = blockIdx.x;   // hand tile group
    const int c   = blockIdx.y;   // obj chunk
    const int b   = blockIdx.z;   // batch
    const int tid = threadIdx.x;
    const int wave = tid >> 6;
    const int lane = tid & 63;

    // per-lane obj stash: 10 float4s, loaded once, reused by all 4 tiles
    const float4* op = otf + (size_t)b * Vpad + c * CHUNKP + tid;
    float4 o[LPP];
#pragma unroll
    for (int k = 0; k < LPP; ++k) o[k] = op[k * BLK];

    const float4* hp = htf + (size_t)b * NHPAD + bx * (G * T);
    float* sw = &s_red[wave][0];
    const int r   = lane & 15;
    const int seg = lane >> 4;

#pragma unroll
    for (int g = 0; g < G; ++g) {
        // hand tile -> SGPRs (uniform address => s_load), one tile at a time
        float4 h[T];
#pragma unroll
        for (int t = 0; t < T; ++t) h[t] = hp[g * T + t];

        float m[T];
#pragma unroll
        for (int t = 0; t < T; ++t) m[t] = 3.4e38f;

#pragma unroll
        for (int k = 0; k < LPP; ++k) {
#pragma unroll
            for (int t = 0; t < T; ++t) {
                float v = fmaf(h[t].x, o[k].x, o[k].w);
                v = fmaf(h[t].y, o[k].y, v);
                v = fmaf(h[t].z, o[k].z, v);
                m[t] = fminf(m[t], v);   // d2' = |o|^2 - 2 h.o
            }
        }

        // fold |h|^2 and transpose: s[t][lane] (row stride 65 -> 2-way, free)
#pragma unroll
        for (int t = 0; t < T; ++t) sw[t * 65 + lane] = m[t] + h[t].w;
        __builtin_amdgcn_wave_barrier();   // wave-synchronous LDS, in-order DS

        // lane reads its quarter-row of hand point r
        float v = 3.4e38f;
        const int base = r * 65 + seg * 16;
#pragma unroll
        for (int j = 0; j < 16; ++j) v = fminf(v, sw[base + j]);
        __builtin_amdgcn_wave_barrier();   // before next tile overwrites

        // combine the 4 segments (lanes r, r+16, r+32, r+48)
        v = fminf(v, __shfl_xor(v, 16));
        v = fminf(v, __shfl_xor(v, 32));

        if (seg == 0) {
            const int hidx = (bx * G + g) * T + r;
            if (hidx < NH) {
                const unsigned bits = __float_as_uint(fmaxf(v, 0.f));
                unsigned int* p = &minb[b * NH + hidx];
                // stale read >= true min => skipping when bits >= *p is safe
                if (bits < *((volatile unsigned int*)p)) atomicMin(p, bits);
            }
        }
    }
}

// ---------------------------------------------------------------------------
// Fallback (ws too small for tf buffers): scalar-pipe kernel on raw obj.
// ---------------------------------------------------------------------------
constexpr int FBLK = 256, FSLOT = 3, FCHUNK = 157;
__global__ __launch_bounds__(FBLK) void nn_min_raw_kernel(
    const float* __restrict__ hand, const float* __restrict__ obj,
    unsigned int* __restrict__ minb, int V)
{
    const int b = blockIdx.y, c = blockIdx.x, tid = threadIdx.x;
    const int j0 = c * FCHUNK;
    const int cnt = min(FCHUNK, V - j0);
    const float* op = obj + ((size_t)b * V + j0) * 3;
    const float* hb = hand + (size_t)b * NH * 3;
    float hx[FSLOT], hy[FSLOT], hz[FSLOT], m[FSLOT];
#pragma unroll
    for (int s = 0; s < FSLOT; ++s) {
        const int h = tid + s * FBLK;
        hx[s] = hb[h * 3 + 0]; hy[s] = hb[h * 3 + 1]; hz[s] = hb[h * 3 + 2];
        m[s] = 3.4e38f;
    }
#pragma unroll 2
    for (int j = 0; j < cnt; ++j) {
        const float ox = op[3 * j + 0], oy = op[3 * j + 1], oz = op[3 * j + 2];
#pragma unroll
        for (int s = 0; s < FSLOT; ++s) {
            const float dx = ox - hx[s], dy = oy - hy[s], dz = oz - hz[s];
            m[s] = fminf(m[s], fmaf(dx, dx, fmaf(dy, dy, dz * dz)));
        }
    }
#pragma unroll
    for (int s = 0; s < FSLOT; ++s) {
        const int h = tid + s * FBLK;
        const unsigned bits = __float_as_uint(fmaxf(m[s], 0.f));
        unsigned int* p = &minb[b * NH + h];
        if (bits < *((volatile unsigned int*)p)) atomicMin(p, bits);
    }
    if (tid < NH - FSLOT * FBLK) {
        const int h = FSLOT * FBLK + tid;
        const float tx = hb[h * 3 + 0], ty = hb[h * 3 + 1], tz = hb[h * 3 + 2];
        float tm = 3.4e38f;
        for (int j = 0; j < cnt; ++j) {
            const float dx = op[3 * j + 0] - tx;
            const float dy = op[3 * j + 1] - ty;
            const float dz = op[3 * j + 2] - tz;
            tm = fminf(tm, fmaf(dx, dx, fmaf(dy, dy, dz * dz)));
        }
        unsigned int* p = &minb[b * NH + h];
        const unsigned bits = __float_as_uint(fmaxf(tm, 0.f));
        if (bits < *((volatile unsigned int*)p)) atomicMin(p, bits);
    }
}

// Final reduction -> 6 scalar outputs
__global__ __launch_bounds__(256) void finalize_kernel(
    const unsigned int* __restrict__ minb, float* __restrict__ out, int B)
{
    constexpr float COLL = 0.005f;
    constexpr float CONT = 0.01f;
    const int total = B * NH;
    const int tid = threadIdx.x;

    double sum_d = 0.0, pen_sum = 0.0, att_sum = 0.0;
    int pen_cnt = 0, att_cnt = 0;
    for (int i = tid; i < total; i += 256) {
        const float d = sqrtf(__uint_as_float(minb[i]));
        sum_d += (double)d;
        if (d < COLL) { const float t = COLL - d; pen_sum += (double)(t * t); pen_cnt++; }
        const int n = i % NH;
        const bool isc = (n == 745) | (n == 317) | (n == 444) | (n == 556) |
                         (n == 673) | (n == 95)  | (n == 182) | (n == 234) |
                         (n == 279) | (n == 320);
        if (isc & (d > COLL) & (d < CONT)) { att_sum += (double)(d * d); att_cnt++; }
    }

    __shared__ double sd[256], sp[256], sa[256];
    __shared__ int    cp[256], ca[256];
    sd[tid] = sum_d; sp[tid] = pen_sum; sa[tid] = att_sum;
    cp[tid] = pen_cnt; ca[tid] = att_cnt;
    __syncthreads();
    for (int off = 128; off > 0; off >>= 1) {
        if (tid < off) {
            sd[tid] += sd[tid + off]; sp[tid] += sp[tid + off];
            sa[tid] += sa[tid + off];
            cp[tid] += cp[tid + off]; ca[tid] += ca[tid + off];
        }
        __syncthreads();
    }
    if (tid == 0) {
        const double pen_loss = cp[0] > 0 ? sp[0] / (double)cp[0] : 0.0;
        const double att_loss = ca[0] > 0 ? sa[0] / (double)ca[0] : 0.0;
        out[0] = (float)(100.0 * pen_loss + 10.0 * att_loss);
        out[1] = (float)pen_loss;
        out[2] = (float)att_loss;
        out[3] = (float)(sd[0] / (double)total);
        out[4] = (float)ca[0];
        out[5] = (float)cp[0];
    }
}

extern "C" void kernel_launch(void* const* d_in, const int* in_sizes, int n_in,
                              void* d_out, int out_size, void* d_ws, size_t ws_size,
                              hipStream_t stream) {
    const float* hand = (const float*)d_in[0];  // [B, 778, 3] fp32
    const float* obj  = (const float*)d_in[1];  // [B, V, 3]   fp32
    // d_in[2]/d_in[3] (faces): unused by the loss

    const int B = in_sizes[0] / (NH * 3);
    const int V = in_sizes[1] / (B * 3);
    const int nchunks = (V + CHUNKP - 1) / CHUNKP;
    const int Vpad = nchunks * CHUNKP;

    unsigned int* minb = (unsigned int*)d_ws;                    // [B*NH]
    float4* htf = (float4*)((char*)d_ws + 65536);                // [B*NHPAD]
    float4* otf = (float4*)((char*)d_ws + 65536 + 131072);       // [B*Vpad]
    const size_t need = 65536 + 131072 + (size_t)B * Vpad * sizeof(float4);

    if (ws_size >= need) {
        const int tot = B * Vpad;
        transform_kernel<<<(tot + 255) / 256, 256, 0, stream>>>(
            hand, obj, otf, htf, minb, V, Vpad, B);
        dim3 grid(NBX, nchunks, B);
        nn_min_kernel<<<grid, BLK, 0, stream>>>(otf, htf, minb, Vpad);
    } else {
        hipMemsetAsync(d_ws, 0x7F, (size_t)B * NH * sizeof(unsigned int), stream);
        dim3 grid((V + FCHUNK - 1) / FCHUNK, B);
        nn_min_raw_kernel<<<grid, FBLK, 0, stream>>>(hand, obj, minb, V);
    }
    finalize_kernel<<<1, 256, 0, stream>>>(minb, (float*)d_out, B);
}